// Round 7
// baseline (6181.359 us; speedup 1.0000x reference)
//
#include <hip/hip_runtime.h>
#include <math.h>

#define N_NODES 50000
#define N_EDGES 800000
#define NBLK    3125      // N_EDGES / 256

__device__ __forceinline__ float silu_f(float x) {
    return x * __fdividef(1.f, 1.f + __expf(-x));
}

// ---------------- K1: per-node pre (s1,v1 -> ws; sc_s,sc_v -> out) ----------
__global__ void __launch_bounds__(256) k_node_pre(
    const float* __restrict__ node_feats,
    const int*   __restrict__ specie,
    const float* __restrict__ Wus,   // 32x32
    const float* __restrict__ Wuv,   // 32x32
    const float* __restrict__ Wss,   // 5x32x32
    const float* __restrict__ Wsv,   // 5x32x32
    float* __restrict__ s1v1,        // N x 128  [s1(32), v1 m*3+c (96)]
    float* __restrict__ out)         // N x 128  gets sc
{
    int n = blockIdx.x * 256 + threadIdx.x;
    if (n >= N_NODES) return;
    int part = blockIdx.y;           // 0 = scalar part, 1..3 = vector c
    const float* nf = node_feats + (size_t)n * 128;
    float* srow = s1v1 + (size_t)n * 128;
    float* orow = out  + (size_t)n * 128;
    int sp = specie[n];
    const float RS32 = 0.17677669529663687f; // 1/sqrt(32)

    if (part == 0) {
        float s[32];
        #pragma unroll
        for (int q = 0; q < 8; ++q) {
            float4 t = *reinterpret_cast<const float4*>(nf + 4*q);
            s[4*q+0]=t.x; s[4*q+1]=t.y; s[4*q+2]=t.z; s[4*q+3]=t.w;
        }
        float acc[32];
        #pragma unroll
        for (int k = 0; k < 32; ++k) acc[k] = 0.f;
        #pragma unroll
        for (int m = 0; m < 32; ++m) {
            float sm = s[m];
            #pragma unroll
            for (int k = 0; k < 32; ++k) acc[k] += sm * Wus[m*32 + k];
        }
        #pragma unroll
        for (int k = 0; k < 32; ++k) srow[k] = acc[k] * RS32;

        const float* Wp = Wss + sp * 1024;
        #pragma unroll
        for (int k = 0; k < 32; ++k) acc[k] = 0.f;
        #pragma unroll
        for (int i = 0; i < 32; ++i) {
            float si = s[i];
            #pragma unroll
            for (int j = 0; j < 32; ++j) acc[j] += si * __ldg(Wp + i*32 + j);
        }
        #pragma unroll
        for (int j = 0; j < 32; ++j) orow[j] = acc[j] * RS32;
    } else {
        int c = part - 1;
        float v[32];
        #pragma unroll
        for (int m = 0; m < 32; ++m) v[m] = nf[32 + m*3 + c];
        float acc[32];
        #pragma unroll
        for (int k = 0; k < 32; ++k) acc[k] = 0.f;
        #pragma unroll
        for (int m = 0; m < 32; ++m) {
            float vm = v[m];
            #pragma unroll
            for (int k = 0; k < 32; ++k) acc[k] += vm * Wuv[m*32 + k];
        }
        #pragma unroll
        for (int k = 0; k < 32; ++k) srow[32 + k*3 + c] = acc[k] * RS32;

        const float* Wp = Wsv + sp * 1024;
        #pragma unroll
        for (int k = 0; k < 32; ++k) acc[k] = 0.f;
        #pragma unroll
        for (int m = 0; m < 32; ++m) {
            float vm = v[m];
            #pragma unroll
            for (int k = 0; k < 32; ++k) acc[k] += vm * __ldg(Wp + m*32 + k);
        }
        #pragma unroll
        for (int k = 0; k < 32; ++k) orow[32 + k*3 + c] = acc[k] * RS32;
    }
}

// ---------------- sort stage: histogram -> scan -> scatter ------------------
__global__ void __launch_bounds__(256) k_hist(
    const int* __restrict__ receivers, int* __restrict__ cnt)
{
    int e = blockIdx.x * 256 + threadIdx.x;   // grid exact
    atomicAdd(&cnt[receivers[e]], 1);
}

__global__ void __launch_bounds__(1024) k_scan(
    const int* __restrict__ cnt, int* __restrict__ off, int* __restrict__ cursor)
{
    __shared__ int lds[1024];
    __shared__ int base_s;
    int t = threadIdx.x;
    if (t == 0) base_s = 0;
    __syncthreads();
    for (int start = 0; start < N_NODES; start += 1024) {
        int i = start + t;
        int c = (i < N_NODES) ? cnt[i] : 0;
        lds[t] = c;
        __syncthreads();
        for (int d = 1; d < 1024; d <<= 1) {
            int v = (t >= d) ? lds[t - d] : 0;
            __syncthreads();
            lds[t] += v;
            __syncthreads();
        }
        int excl = base_s + lds[t] - c;
        if (i < N_NODES) { off[i] = excl; cursor[i] = 0; }
        __syncthreads();
        if (t == 0) base_s += lds[1023];
        __syncthreads();
    }
    if (t == 0) off[N_NODES] = base_s;
}

__global__ void __launch_bounds__(256) k_scatter(
    const float* __restrict__ vectors, const int* __restrict__ senders,
    const int* __restrict__ receivers, const int* __restrict__ off,
    int* __restrict__ cursor, float4* __restrict__ sortedVS,
    int* __restrict__ sortedR)
{
    int e = blockIdx.x * 256 + threadIdx.x;   // grid exact
    int r = receivers[e];
    int pos = off[r] + atomicAdd(&cursor[r], 1);
    float4 vs;
    vs.x = vectors[3*e+0]; vs.y = vectors[3*e+1]; vs.z = vectors[3*e+2];
    vs.w = __int_as_float(senders[e]);
    sortedVS[pos] = vs;
    sortedR[pos]  = r;
}

// ---------------- K2: fused per-edge MLP + segmented-sum aggregation --------
// Edges receiver-sorted. Each message component is segment-summed across the
// wave via 6-step shfl scan; tail lanes own the segment total:
//   wave-interior segment  -> exclusive direct store to agg
//   wave-first/last seg    -> LDS row, merged block-wide after barrier
//   block-boundary recv    -> gparts partial row (folded in k_node_post)
__global__ void __launch_bounds__(256) k_edge(
    const float4* __restrict__ sortedVS,
    const int*   __restrict__ sortedR,
    const float* __restrict__ W1,    // 8x64
    const float* __restrict__ W2,    // 64x64
    const float* __restrict__ W3,    // 64x64
    const float* __restrict__ W4,    // 64x128
    const float* __restrict__ s1v1,  // N x 128
    const int*   __restrict__ off,
    float* __restrict__ agg,         // N x 256
    float* __restrict__ gparts,      // NBLK x 2 x 256
    int*   __restrict__ gid)         // NBLK x 2
{
    __shared__ float rows_s[8][256];
    __shared__ int   sid_s[8];
    __shared__ int   firstR_s;

    int t    = threadIdx.x;
    int blk  = blockIdx.x;
    int s0   = blk * 256;
    int slot = s0 + t;
    int lane = t & 63;
    int w    = t >> 6;

    if (t == 0) {
        gid[2*blk] = -1; gid[2*blk+1] = -1;
        firstR_s = sortedR[s0];
    }

    int rcv = sortedR[slot];

    // ---- segment structure (per wave) ----
    int prevR = __shfl_up(rcv, 1);
    bool head = (lane == 0) || (rcv != prevR);
    bool f = head;
    bool take[6];
    #pragma unroll
    for (int s = 0; s < 6; ++s) {
        int d = 1 << s;
        int fup = __shfl_up((int)f, d);
        take[s] = (lane >= d) && (!f);
        f = f || ((lane >= d) && (fup != 0));
    }
    unsigned long long hb = __ballot(head);
    bool tail = (lane == 63) ? true : (((hb >> (lane + 1)) & 1ull) != 0);
    unsigned long long below = hb & (~0ull >> (63 - lane));
    int headLane = 63 - __clzll((long long)below);
    bool segFirst = (headLane == 0);

    if (tail && segFirst) sid_s[2*w] = rcv;
    if (lane == 63)       sid_s[2*w+1] = segFirst ? -1 : rcv;

    auto emit = [&](int comp, float v) {
        #pragma unroll
        for (int s = 0; s < 6; ++s) {
            float vu = __shfl_up(v, 1 << s);
            if (take[s]) v += vu;
        }
        if (tail) {
            if (segFirst)        rows_s[2*w][comp]   = v;
            else if (lane == 63) rows_s[2*w+1][comp] = v;
            else                 agg[(size_t)rcv * 256 + comp] = v;
        }
    };

    // ---- per-edge geometry + radial ----
    float4 vs = sortedVS[slot];
    float vx = vs.x, vy = vs.y, vz = vs.z;
    int snd = __float_as_int(vs.w);

    float x2 = vx*vx + vy*vy + vz*vz;
    float len = sqrtf(x2 == 0.f ? 1.f : x2);
    float invl = 1.f / len;
    float l2v = len*len, l3v = l2v*len, l6 = l3v*l3v;
    float env = (len < 1.f) ? (1.f - 28.f*l6 + 48.f*l6*len - 21.f*l6*l2v) : 0.f;

    const float SQRT2 = 1.4142135623730951f;
    const float PI    = 3.14159265358979f;
    float radial[8];
    #pragma unroll
    for (int nb = 0; nb < 8; ++nb)
        radial[nb] = SQRT2 * __sinf(PI * (float)(nb+1) * len) * invl * env;

    const float SQ3 = 1.7320508075688772f;
    float shx = SQ3 * vx * invl;
    float shy = SQ3 * vy * invl;
    float shz = SQ3 * vz * invl;

    const float RS8  = 0.35355339059327373f;  // 1/sqrt(8)
    const float RS64 = 0.125f;                // 1/sqrt(64)
    const float RS3  = 0.5773502691896258f;   // 1/sqrt(3)

    float A[64], B[64];

    // layer 1 -> A (h1)
    #pragma unroll
    for (int j = 0; j < 64; ++j) A[j] = 0.f;
    #pragma unroll
    for (int i2 = 0; i2 < 8; ++i2) {
        float hi = radial[i2];
        #pragma unroll
        for (int j = 0; j < 64; ++j) A[j] += hi * W1[i2*64 + j];
    }
    #pragma unroll
    for (int j = 0; j < 64; ++j) A[j] = silu_f(A[j] * RS8);

    // layer 2 -> B (h2)
    #pragma unroll
    for (int j = 0; j < 64; ++j) B[j] = 0.f;
    #pragma unroll
    for (int i2 = 0; i2 < 64; ++i2) {
        float hi = A[i2];
        #pragma unroll
        for (int j = 0; j < 64; ++j) B[j] += hi * W2[i2*64 + j];
    }
    #pragma unroll
    for (int j = 0; j < 64; ++j) B[j] = silu_f(B[j] * RS64);

    // layer 3 -> A (h3)
    #pragma unroll
    for (int j = 0; j < 64; ++j) A[j] = 0.f;
    #pragma unroll
    for (int i2 = 0; i2 < 64; ++i2) {
        float hi = B[i2];
        #pragma unroll
        for (int j = 0; j < 64; ++j) A[j] += hi * W3[i2*64 + j];
    }
    #pragma unroll
    for (int j = 0; j < 64; ++j) A[j] = silu_f(A[j] * RS64);

    // mix_v (W4 cols 64..128) -> B
    #pragma unroll
    for (int j = 0; j < 64; ++j) B[j] = 0.f;
    #pragma unroll
    for (int i2 = 0; i2 < 64; ++i2) {
        float hi = A[i2];
        #pragma unroll
        for (int j = 0; j < 64; ++j) B[j] += hi * W4[i2*128 + 64 + j];
    }
    #pragma unroll
    for (int j = 0; j < 64; ++j) B[j] *= RS64;

    const float* srow = s1v1 + (size_t)snd * 128;

    // ms -> C
    float C[32];
    #pragma unroll
    for (int q = 0; q < 8; ++q) {
        float4 tt = *reinterpret_cast<const float4*>(srow + 4*q);
        C[4*q+0]=tt.x; C[4*q+1]=tt.y; C[4*q+2]=tt.z; C[4*q+3]=tt.w;
    }

    // mv rows (v rows 0..31): comps 64+3m+c; also tp_s -> D
    float D[32];
    #pragma unroll
    for (int b = 0; b < 4; ++b) {
        float bat[24];
        #pragma unroll
        for (int q = 0; q < 6; ++q) {
            float4 tt = *reinterpret_cast<const float4*>(srow + 32 + b*24 + 4*q);
            bat[4*q+0]=tt.x; bat[4*q+1]=tt.y; bat[4*q+2]=tt.z; bat[4*q+3]=tt.w;
        }
        #pragma unroll
        for (int mm = 0; mm < 8; ++mm) {
            int m = b*8 + mm;
            float mvx = bat[3*mm+0], mvy = bat[3*mm+1], mvz = bat[3*mm+2];
            D[m] = (mvx*shx + mvy*shy + mvz*shz) * RS3;
            float fv = B[m];
            emit(64 + 3*m + 0, mvx*fv);
            emit(64 + 3*m + 1, mvy*fv);
            emit(64 + 3*m + 2, mvz*fv);
        }
    }

    // tp_v rows (v rows 32..63): comps 160+3m+c
    #pragma unroll
    for (int m = 0; m < 32; ++m) {
        float fv = C[m] * B[32+m];
        emit(160 + 3*m + 0, fv*shx);
        emit(160 + 3*m + 1, fv*shy);
        emit(160 + 3*m + 2, fv*shz);
    }

    // mix_s (W4 cols 0..64) -> B
    #pragma unroll
    for (int j = 0; j < 64; ++j) B[j] = 0.f;
    #pragma unroll
    for (int i2 = 0; i2 < 64; ++i2) {
        float hi = A[i2];
        #pragma unroll
        for (int j = 0; j < 64; ++j) B[j] += hi * W4[i2*128 + j];
    }
    #pragma unroll
    for (int j = 0; j < 64; ++j) B[j] *= RS64;

    // scalar comps 0..63
    #pragma unroll
    for (int j = 0; j < 32; ++j) emit(j, C[j] * B[j]);
    #pragma unroll
    for (int j = 0; j < 32; ++j) emit(32 + j, D[j] * B[32+j]);

    // ---- block-level merge of wave-boundary partial rows ----
    __syncthreads();
    auto flushf = [&](int id, float v) {
        if (id < 0) return;
        int p0 = off[id], p1 = off[id+1];
        if (p0 >= s0 && p1 <= s0 + 256) {
            agg[(size_t)id * 256 + t] = v;
        } else {
            int sl = (id == firstR_s) ? 0 : 1;
            gparts[((size_t)(2*blk + sl)) * 256 + t] = v;
            if (t == 0) gid[2*blk + sl] = id;
        }
    };
    int runId = -2; float run = 0.f;
    #pragma unroll
    for (int r = 0; r < 8; ++r) {
        int id = sid_s[r];
        if (id < 0) continue;
        float val = rows_s[r][t];
        if (id == runId) run += val;
        else { flushf(runId, run); runId = id; run = val; }
    }
    flushf(runId, run);
}

// ---------------- K3: per-node post (assemble agg, down-proj, gate) ---------
__global__ void __launch_bounds__(256) k_node_post(
    const float* __restrict__ agg,     // N x 256
    const float* __restrict__ gparts,  // NBLK x 2 x 256
    const int*   __restrict__ gid,     // NBLK x 2
    const int*   __restrict__ off,
    const float* __restrict__ Wds,     // 64x64
    const float* __restrict__ Wdv,     // 64x32
    float* __restrict__ out)           // N x 128 (holds sc from K1)
{
    int n = blockIdx.x;
    int t = threadIdx.x;
    __shared__ float a_s[256];
    __shared__ float gl[32];

    int p0 = off[n], p1 = off[n+1];
    float a = 0.f;
    if (p1 > p0) {
        int b0 = p0 >> 8, b1 = (p1 - 1) >> 8;
        if (b0 == b1) {
            a = agg[(size_t)n * 256 + t];
        } else {
            for (int b = b0; b <= b1; ++b) {
                if (gid[2*b]   == n) a += gparts[((size_t)(2*b))   * 256 + t];
                if (gid[2*b+1] == n) a += gparts[((size_t)(2*b+1)) * 256 + t];
            }
        }
    }
    a_s[t] = a;
    __syncthreads();

    const float SC = 0.03125f;       // (1/sqrt(16)) * (1/sqrt(64))
    float* orow = out + (size_t)n * 128;

    float dv = 0.f;
    if (t < 64) {
        float acc = 0.f;
        #pragma unroll
        for (int m = 0; m < 64; ++m) acc += a_s[m] * Wds[m*64 + t];
        float sv = silu_f(acc * SC);
        if (t < 32) orow[t] += sv;       // feat + sc_s
        else        gl[t - 32] = sv;     // g
    } else if (t < 160) {
        int kc = t - 64;                 // = k*3 + c
        int k = kc / 3, c = kc - 3*k;
        float acc = 0.f;
        #pragma unroll
        for (int m = 0; m < 64; ++m) acc += a_s[64 + m*3 + c] * Wdv[m*32 + k];
        dv = acc * SC;
    }
    __syncthreads();
    if (t >= 64 && t < 160) {
        int kc = t - 64;
        int k = kc / 3;
        orow[32 + kc] += dv * gl[k];     // gv + sc_v
    }
}

extern "C" void kernel_launch(void* const* d_in, const int* in_sizes, int n_in,
                              void* d_out, int out_size, void* d_ws, size_t ws_size,
                              hipStream_t stream) {
    const float* vectors    = (const float*)d_in[0];
    const float* node_feats = (const float*)d_in[1];
    const float* W_skip_s   = (const float*)d_in[2];
    const float* W_skip_v   = (const float*)d_in[3];
    const float* W_up_s     = (const float*)d_in[4];
    const float* W_up_v     = (const float*)d_in[5];
    const float* W_mlp1     = (const float*)d_in[6];
    const float* W_mlp2     = (const float*)d_in[7];
    const float* W_mlp3     = (const float*)d_in[8];
    const float* W_mlp4     = (const float*)d_in[9];
    const float* W_down_s   = (const float*)d_in[10];
    const float* W_down_v   = (const float*)d_in[11];
    const int*   node_specie= (const int*)d_in[12];
    const int*   senders    = (const int*)d_in[13];
    const int*   receivers  = (const int*)d_in[14];
    float* out = (float*)d_out;

    // workspace layout (~100 MB)
    float*  s1v1     = (float*)d_ws;                                   // N*128
    float*  agg      = s1v1 + (size_t)N_NODES * 128;                   // N*256
    float4* sortedVS = (float4*)(agg + (size_t)N_NODES * 256);         // E
    int*    sortedR  = (int*)(sortedVS + N_EDGES);                     // E
    float*  gparts   = (float*)(sortedR + N_EDGES);                    // NBLK*2*256
    int*    cnt      = (int*)(gparts + (size_t)NBLK * 2 * 256);        // N
    int*    cursor   = cnt + N_NODES;                                  // N
    int*    off      = cursor + N_NODES;                               // N+1
    int*    gid      = off + N_NODES + 1;                              // NBLK*2

    hipMemsetAsync(cnt, 0, (size_t)N_NODES * sizeof(int), stream);

    dim3 gn((N_NODES + 255) / 256, 4);
    k_node_pre<<<gn, 256, 0, stream>>>(node_feats, node_specie, W_up_s, W_up_v,
                                       W_skip_s, W_skip_v, s1v1, out);
    k_hist<<<NBLK, 256, 0, stream>>>(receivers, cnt);
    k_scan<<<1, 1024, 0, stream>>>(cnt, off, cursor);
    k_scatter<<<NBLK, 256, 0, stream>>>(vectors, senders, receivers,
                                        off, cursor, sortedVS, sortedR);
    k_edge<<<NBLK, 256, 0, stream>>>(sortedVS, sortedR, W_mlp1, W_mlp2, W_mlp3,
                                     W_mlp4, s1v1, off, agg, gparts, gid);
    k_node_post<<<N_NODES, 256, 0, stream>>>(agg, gparts, gid, off,
                                             W_down_s, W_down_v, out);
}

// Round 8
// 2089.486 us; speedup vs baseline: 2.9583x; 2.9583x over previous
//
#include <hip/hip_runtime.h>
#include <math.h>
#include <stdint.h>

#define N_NODES 50000
#define N_EDGES 800000
#define PLSTRIDE 132   // floats per edge payload
#define PL_SM  0       // smsg[64]
#define PL_B   64      // b[32] = mixv[0:32]
#define PL_A   96      // a[32] = C*mixv[32:64]
#define PL_SH  128     // sh[3]
#define PL_SND 131     // int
#define MLP_LDS 81920

__device__ __forceinline__ float silu_f(float x) {
    return x * __fdividef(1.f, 1.f + __expf(-x));
}

// ---------------- K1: per-node pre (s1,v1 -> ws; sc_s,sc_v -> out) ----------
__global__ void __launch_bounds__(256) k_node_pre(
    const float* __restrict__ node_feats,
    const int*   __restrict__ specie,
    const float* __restrict__ Wus,   // 32x32
    const float* __restrict__ Wuv,   // 32x32
    const float* __restrict__ Wss,   // 5x32x32
    const float* __restrict__ Wsv,   // 5x32x32
    float* __restrict__ s1v1,        // N x 128  [s1(32), v1 m*3+c (96)]
    float* __restrict__ out)         // N x 128  gets sc
{
    int n = blockIdx.x * 256 + threadIdx.x;
    if (n >= N_NODES) return;
    int part = blockIdx.y;           // 0 = scalar part, 1..3 = vector c
    const float* nf = node_feats + (size_t)n * 128;
    float* srow = s1v1 + (size_t)n * 128;
    float* orow = out  + (size_t)n * 128;
    int sp = specie[n];
    const float RS32 = 0.17677669529663687f; // 1/sqrt(32)

    if (part == 0) {
        float s[32];
        #pragma unroll
        for (int q = 0; q < 8; ++q) {
            float4 t = *reinterpret_cast<const float4*>(nf + 4*q);
            s[4*q+0]=t.x; s[4*q+1]=t.y; s[4*q+2]=t.z; s[4*q+3]=t.w;
        }
        float acc[32];
        #pragma unroll
        for (int k = 0; k < 32; ++k) acc[k] = 0.f;
        #pragma unroll
        for (int m = 0; m < 32; ++m) {
            float sm = s[m];
            #pragma unroll
            for (int k = 0; k < 32; ++k) acc[k] += sm * Wus[m*32 + k];
        }
        #pragma unroll
        for (int k = 0; k < 32; ++k) srow[k] = acc[k] * RS32;

        const float* Wp = Wss + sp * 1024;
        #pragma unroll
        for (int k = 0; k < 32; ++k) acc[k] = 0.f;
        #pragma unroll
        for (int i = 0; i < 32; ++i) {
            float si = s[i];
            #pragma unroll
            for (int j = 0; j < 32; ++j) acc[j] += si * __ldg(Wp + i*32 + j);
        }
        #pragma unroll
        for (int j = 0; j < 32; ++j) orow[j] = acc[j] * RS32;
    } else {
        int c = part - 1;
        float v[32];
        #pragma unroll
        for (int m = 0; m < 32; ++m) v[m] = nf[32 + m*3 + c];
        float acc[32];
        #pragma unroll
        for (int k = 0; k < 32; ++k) acc[k] = 0.f;
        #pragma unroll
        for (int m = 0; m < 32; ++m) {
            float vm = v[m];
            #pragma unroll
            for (int k = 0; k < 32; ++k) acc[k] += vm * Wuv[m*32 + k];
        }
        #pragma unroll
        for (int k = 0; k < 32; ++k) srow[32 + k*3 + c] = acc[k] * RS32;

        const float* Wp = Wsv + sp * 1024;
        #pragma unroll
        for (int k = 0; k < 32; ++k) acc[k] = 0.f;
        #pragma unroll
        for (int m = 0; m < 32; ++m) {
            float vm = v[m];
            #pragma unroll
            for (int k = 0; k < 32; ++k) acc[k] += vm * __ldg(Wp + m*32 + k);
        }
        #pragma unroll
        for (int k = 0; k < 32; ++k) orow[32 + k*3 + c] = acc[k] * RS32;
    }
}

// ---------------- sort stage: histogram -> scan -> scatter ------------------
__global__ void __launch_bounds__(256) k_hist(
    const int* __restrict__ receivers, int* __restrict__ cnt)
{
    int e = blockIdx.x * 256 + threadIdx.x;   // grid exact
    atomicAdd(&cnt[receivers[e]], 1);
}

__global__ void __launch_bounds__(1024) k_scan(
    const int* __restrict__ cnt, int* __restrict__ off, int* __restrict__ cursor)
{
    __shared__ int lds[1024];
    __shared__ int base_s;
    int t = threadIdx.x;
    if (t == 0) base_s = 0;
    __syncthreads();
    for (int start = 0; start < N_NODES; start += 1024) {
        int i = start + t;
        int c = (i < N_NODES) ? cnt[i] : 0;
        lds[t] = c;
        __syncthreads();
        for (int d = 1; d < 1024; d <<= 1) {
            int v = (t >= d) ? lds[t - d] : 0;
            __syncthreads();
            lds[t] += v;
            __syncthreads();
        }
        int excl = base_s + lds[t] - c;
        if (i < N_NODES) { off[i] = excl; cursor[i] = 0; }
        __syncthreads();
        if (t == 0) base_s += lds[1023];
        __syncthreads();
    }
    if (t == 0) off[N_NODES] = base_s;
}

__global__ void __launch_bounds__(256) k_scatter(
    const float* __restrict__ vectors, const int* __restrict__ senders,
    const int* __restrict__ receivers, const int* __restrict__ off,
    int* __restrict__ cursor, float4* __restrict__ sortedVS)
{
    int e = blockIdx.x * 256 + threadIdx.x;   // grid exact
    int r = receivers[e];
    int pos = off[r] + atomicAdd(&cursor[r], 1);
    float4 vs;
    vs.x = vectors[3*e+0]; vs.y = vectors[3*e+1]; vs.z = vectors[3*e+2];
    vs.w = __int_as_float(senders[e]);
    sortedVS[pos] = vs;
}

// ---------------- K2: tiled fp32 GEMM MLP over 128-edge blocks --------------
// LDS: bufA[64][128] | bufB[64][128] | Wl[64][64]  = 80 KB (2 blocks/CU)
// thread microtile: 4 edges x 8 neurons. Epilogue writes 528B payload/edge.
__global__ void __launch_bounds__(256, 2) k_mlp(
    const float4* __restrict__ sortedVS,
    const float* __restrict__ W1,    // 8x64
    const float* __restrict__ W2,    // 64x64
    const float* __restrict__ W3,    // 64x64
    const float* __restrict__ W4,    // 64x128
    const float* __restrict__ s1v1,  // N x 128
    float* __restrict__ payload,     // chunk rows x 132
    int r0)
{
    extern __shared__ float lds[];
    float* bufA = lds;           // 64*128
    float* bufB = lds + 8192;    // 64*128
    float* Wl   = lds + 16384;   // 64*64
    int t  = threadIdx.x;
    int e0 = (t & 31) * 4;
    int j0 = (t >> 5) * 8;
    int s0 = r0 + blockIdx.x * 128;
    float* payBlk = payload + (size_t)blockIdx.x * 128 * PLSTRIDE;

    const float RS8  = 0.35355339059327373f;
    const float RS64 = 0.125f;
    const float RS3  = 0.5773502691896258f;

    // ---- phase A: radial -> bufA rows 0..7 ; sh,snd -> payload ; W1 -> Wl --
    if (t < 128) {
        int e = t;
        float4 vs = sortedVS[s0 + e];
        float vx = vs.x, vy = vs.y, vz = vs.z;
        float x2 = vx*vx + vy*vy + vz*vz;
        float len = sqrtf(x2 == 0.f ? 1.f : x2);
        float invl = 1.f / len;
        float l2v = len*len, l3v = l2v*len, l6 = l3v*l3v;
        float env = (len < 1.f) ? (1.f - 28.f*l6 + 48.f*l6*len - 21.f*l6*l2v) : 0.f;
        const float SQRT2 = 1.4142135623730951f;
        const float PI    = 3.14159265358979f;
        #pragma unroll
        for (int nb = 0; nb < 8; ++nb)
            bufA[nb*128 + e] = SQRT2 * __sinf(PI * (float)(nb+1) * len) * invl * env;
        const float SQ3 = 1.7320508075688772f;
        float* pe = payBlk + (size_t)e * PLSTRIDE;
        pe[PL_SH+0] = SQ3 * vx * invl;
        pe[PL_SH+1] = SQ3 * vy * invl;
        pe[PL_SH+2] = SQ3 * vz * invl;
        ((int*)pe)[PL_SND] = __float_as_int(vs.w);
    } else {
        int i = t - 128;   // 128 float4 = 512 floats of W1
        reinterpret_cast<float4*>(Wl)[i] = reinterpret_cast<const float4*>(W1)[i];
    }
    __syncthreads();

    float acc[8][4];
    auto gemm = [&](const float* Xb, int kd) {
        #pragma unroll
        for (int jj = 0; jj < 8; ++jj)
            #pragma unroll
            for (int ee = 0; ee < 4; ++ee) acc[jj][ee] = 0.f;
        for (int k = 0; k < kd; ++k) {
            float4 xa = *reinterpret_cast<const float4*>(Xb + k*128 + e0);
            float4 w0 = *reinterpret_cast<const float4*>(Wl + k*64 + j0);
            float4 w1 = *reinterpret_cast<const float4*>(Wl + k*64 + j0 + 4);
            float w[8] = {w0.x,w0.y,w0.z,w0.w,w1.x,w1.y,w1.z,w1.w};
            float x[4] = {xa.x,xa.y,xa.z,xa.w};
            #pragma unroll
            for (int jj = 0; jj < 8; ++jj)
                #pragma unroll
                for (int ee = 0; ee < 4; ++ee) acc[jj][ee] += w[jj]*x[ee];
        }
    };
    auto act_store = [&](float* Yb, float sc) {
        #pragma unroll
        for (int jj = 0; jj < 8; ++jj) {
            float4 o;
            o.x = silu_f(acc[jj][0]*sc); o.y = silu_f(acc[jj][1]*sc);
            o.z = silu_f(acc[jj][2]*sc); o.w = silu_f(acc[jj][3]*sc);
            *reinterpret_cast<float4*>(Yb + (j0+jj)*128 + e0) = o;
        }
    };
    auto stageW = [&](const float* Wg) {       // 64x64 row-major
        #pragma unroll
        for (int i = t; i < 1024; i += 256)
            reinterpret_cast<float4*>(Wl)[i] = reinterpret_cast<const float4*>(Wg)[i];
    };
    auto stageW4 = [&](int q0) {               // W4 cols q0*4 .. q0*4+63
        #pragma unroll
        for (int i = t; i < 1024; i += 256) {
            int k = i >> 4, jq = i & 15;
            reinterpret_cast<float4*>(Wl)[i] =
                reinterpret_cast<const float4*>(W4)[k*32 + q0 + jq];
        }
    };

    // L1: radial(8) -> h1
    gemm(bufA, 8);
    __syncthreads();
    act_store(bufB, RS8);
    stageW(W2);
    __syncthreads();
    // L2: h1 -> h2
    gemm(bufB, 64);
    __syncthreads();
    act_store(bufA, RS64);
    stageW(W3);
    __syncthreads();
    // L3: h2 -> h3
    gemm(bufA, 64);
    __syncthreads();
    act_store(bufB, RS64);
    stageW4(0);
    __syncthreads();

    // pass 4a: mix_s = h3 @ W4[:,0:64] * RS64 ; epilogue -> smsg
    gemm(bufB, 64);
    #pragma unroll
    for (int ee = 0; ee < 4; ++ee) {
        int e = e0 + ee;
        float* pe = payBlk + (size_t)e * PLSTRIDE;
        int snd = ((const int*)pe)[PL_SND];
        const float* row = s1v1 + (size_t)snd * 128;
        float o[8];
        if (j0 < 32) {
            float4 c0 = *reinterpret_cast<const float4*>(row + j0);
            float4 c1 = *reinterpret_cast<const float4*>(row + j0 + 4);
            float cc[8] = {c0.x,c0.y,c0.z,c0.w,c1.x,c1.y,c1.z,c1.w};
            #pragma unroll
            for (int jj = 0; jj < 8; ++jj) o[jj] = cc[jj] * acc[jj][ee] * RS64;
        } else {
            float shx = pe[PL_SH], shy = pe[PL_SH+1], shz = pe[PL_SH+2];
            int base = 3*j0 - 64;            // 32 + 3*(j0-32), 16B aligned
            float r[28];
            #pragma unroll
            for (int q = 0; q < 7; ++q)
                *reinterpret_cast<float4*>(r + 4*q) =
                    *reinterpret_cast<const float4*>(row + base + 4*q);
            #pragma unroll
            for (int jj = 0; jj < 8; ++jj) {
                float D = (r[3*jj]*shx + r[3*jj+1]*shy + r[3*jj+2]*shz) * RS3;
                o[jj] = D * acc[jj][ee] * RS64;
            }
        }
        *reinterpret_cast<float4*>(pe + PL_SM + j0)     = make_float4(o[0],o[1],o[2],o[3]);
        *reinterpret_cast<float4*>(pe + PL_SM + j0 + 4) = make_float4(o[4],o[5],o[6],o[7]);
    }
    __syncthreads();
    stageW4(16);
    __syncthreads();

    // pass 4b: mix_v = h3 @ W4[:,64:128] * RS64 ; epilogue -> b (m<32), a (m>=32)
    gemm(bufB, 64);
    #pragma unroll
    for (int ee = 0; ee < 4; ++ee) {
        int e = e0 + ee;
        float* pe = payBlk + (size_t)e * PLSTRIDE;
        float o[8];
        if (j0 < 32) {
            #pragma unroll
            for (int jj = 0; jj < 8; ++jj) o[jj] = acc[jj][ee] * RS64;
            *reinterpret_cast<float4*>(pe + PL_B + j0)     = make_float4(o[0],o[1],o[2],o[3]);
            *reinterpret_cast<float4*>(pe + PL_B + j0 + 4) = make_float4(o[4],o[5],o[6],o[7]);
        } else {
            int snd = ((const int*)pe)[PL_SND];
            const float* row = s1v1 + (size_t)snd * 128;
            int m0 = j0 - 32;
            float4 c0 = *reinterpret_cast<const float4*>(row + m0);
            float4 c1 = *reinterpret_cast<const float4*>(row + m0 + 4);
            float cc[8] = {c0.x,c0.y,c0.z,c0.w,c1.x,c1.y,c1.z,c1.w};
            #pragma unroll
            for (int jj = 0; jj < 8; ++jj) o[jj] = cc[jj] * acc[jj][ee] * RS64;
            *reinterpret_cast<float4*>(pe + PL_A + m0)     = make_float4(o[0],o[1],o[2],o[3]);
            *reinterpret_cast<float4*>(pe + PL_A + m0 + 4) = make_float4(o[4],o[5],o[6],o[7]);
        }
    }
}

// ---------------- K2b: per-(node,comp) aggregation from payload -------------
__global__ void __launch_bounds__(256) k_agg(
    const float* __restrict__ payload,
    const float* __restrict__ s1v1,
    const int*   __restrict__ off,
    float* __restrict__ agg,         // N x 256
    int r0, int r1, int first)
{
    int t = threadIdx.x;
    int n = blockIdx.x * 64 + (t & 63);
    if (n >= N_NODES) return;
    int jbase = blockIdx.y * 64 + (t >> 6) * 16;
    int p0 = off[n], p1 = off[n+1];
    int lo = p0 > r0 ? p0 : r0;
    int hi = p1 < r1 ? p1 : r1;
    if (!first && lo >= hi) return;
    bool needRow = (jbase < 160) && (jbase + 16 > 64);

    float s[16];
    #pragma unroll
    for (int jj = 0; jj < 16; ++jj) s[jj] = 0.f;

    for (int p = lo; p < hi; ++p) {
        const float* pe = payload + (size_t)(p - r0) * PLSTRIDE;
        const float* row = needRow
            ? s1v1 + (size_t)((const int*)pe)[PL_SND] * 128 : (const float*)0;
        #pragma unroll
        for (int jj = 0; jj < 16; ++jj) {
            int comp = jbase + jj;
            float v;
            if (comp < 64) {
                v = pe[PL_SM + comp];
            } else if (comp < 160) {
                int mc = comp - 64;
                v = row[32 + mc] * pe[PL_B + mc/3];
            } else {
                int mc = comp - 160;
                int m = mc/3;
                v = pe[PL_A + m] * pe[PL_SH + mc - 3*m];
            }
            s[jj] += v;
        }
    }
    float* ap = agg + (size_t)n * 256 + jbase;
    #pragma unroll
    for (int jj = 0; jj < 16; ++jj) {
        if (first) ap[jj] = s[jj];
        else       ap[jj] += s[jj];
    }
}

// ---------------- K3: per-node post (down-proj, gate, += into out) ----------
__global__ void __launch_bounds__(256) k_node_post(
    const float* __restrict__ agg,   // N x 256
    const float* __restrict__ Wds,   // 64x64
    const float* __restrict__ Wdv,   // 64x32
    float* __restrict__ out)         // N x 128 (holds sc from K1)
{
    int n = blockIdx.x;
    int t = threadIdx.x;
    __shared__ float a_s[256];
    __shared__ float gl[32];

    a_s[t] = agg[(size_t)n * 256 + t];
    __syncthreads();

    const float SC = 0.03125f;       // (1/sqrt(16)) * (1/sqrt(64))
    float* orow = out + (size_t)n * 128;

    float dv = 0.f;
    if (t < 64) {
        float acc = 0.f;
        #pragma unroll
        for (int m = 0; m < 64; ++m) acc += a_s[m] * Wds[m*64 + t];
        float sv = silu_f(acc * SC);
        if (t < 32) orow[t] += sv;       // feat + sc_s
        else        gl[t - 32] = sv;     // g
    } else if (t < 160) {
        int kc = t - 64;                 // = k*3 + c
        int k = kc / 3, c = kc - 3*k;
        float acc = 0.f;
        #pragma unroll
        for (int m = 0; m < 64; ++m) acc += a_s[64 + m*3 + c] * Wdv[m*32 + k];
        dv = acc * SC;
    }
    __syncthreads();
    if (t >= 64 && t < 160) {
        int kc = t - 64;
        int k = kc / 3;
        orow[32 + kc] += dv * gl[k];     // gv + sc_v
    }
}

extern "C" void kernel_launch(void* const* d_in, const int* in_sizes, int n_in,
                              void* d_out, int out_size, void* d_ws, size_t ws_size,
                              hipStream_t stream) {
    const float* vectors    = (const float*)d_in[0];
    const float* node_feats = (const float*)d_in[1];
    const float* W_skip_s   = (const float*)d_in[2];
    const float* W_skip_v   = (const float*)d_in[3];
    const float* W_up_s     = (const float*)d_in[4];
    const float* W_up_v     = (const float*)d_in[5];
    const float* W_mlp1     = (const float*)d_in[6];
    const float* W_mlp2     = (const float*)d_in[7];
    const float* W_mlp3     = (const float*)d_in[8];
    const float* W_mlp4     = (const float*)d_in[9];
    const float* W_down_s   = (const float*)d_in[10];
    const float* W_down_v   = (const float*)d_in[11];
    const int*   node_specie= (const int*)d_in[12];
    const int*   senders    = (const int*)d_in[13];
    const int*   receivers  = (const int*)d_in[14];
    float* out = (float*)d_out;

    // workspace layout
    float*  s1v1     = (float*)d_ws;                                   // N*128
    float*  agg      = s1v1 + (size_t)N_NODES * 128;                   // N*256
    float4* sortedVS = (float4*)(agg + (size_t)N_NODES * 256);         // E
    int*    cnt      = (int*)(sortedVS + N_EDGES);                     // N
    int*    cursor   = cnt + N_NODES;                                  // N
    int*    off      = cursor + N_NODES;                               // N+1
    char*   pb       = (char*)(off + N_NODES + 1);
    pb = (char*)(((uintptr_t)pb + 255) & ~(uintptr_t)255);
    float*  payload  = (float*)pb;

    size_t base_bytes = (size_t)(pb - (char*)d_ws);
    size_t margin = 1 << 20;
    size_t avail = (ws_size > base_bytes + margin) ? (ws_size - base_bytes - margin) : 0;
    long cap = (long)(avail / (PLSTRIDE * 4));
    if (cap > N_EDGES) cap = N_EDGES;
    if (cap < 12800)   cap = 12800;            // assume ws >= ~100 MB
    int  chunks = (int)((N_EDGES + cap - 1) / cap);
    long rows   = (((N_EDGES + chunks - 1) / chunks) + 127) & ~127L;   // mult of 128
    chunks = (int)((N_EDGES + rows - 1) / rows);

    hipFuncSetAttribute((const void*)k_mlp,
                        hipFuncAttributeMaxDynamicSharedMemorySize, MLP_LDS);

    hipMemsetAsync(cnt, 0, (size_t)N_NODES * sizeof(int), stream);

    dim3 gn((N_NODES + 255) / 256, 4);
    k_node_pre<<<gn, 256, 0, stream>>>(node_feats, node_specie, W_up_s, W_up_v,
                                       W_skip_s, W_skip_v, s1v1, out);
    k_hist<<<N_EDGES / 256, 256, 0, stream>>>(receivers, cnt);
    k_scan<<<1, 1024, 0, stream>>>(cnt, off, cursor);
    k_scatter<<<N_EDGES / 256, 256, 0, stream>>>(vectors, senders, receivers,
                                                 off, cursor, sortedVS);
    dim3 ga((N_NODES + 63) / 64, 4);
    for (int c = 0; c < chunks; ++c) {
        int r0 = (int)(c * rows);
        int r1 = (int)(r0 + rows); if (r1 > N_EDGES) r1 = N_EDGES;
        int nb = (r1 - r0) / 128;
        k_mlp<<<nb, 256, MLP_LDS, stream>>>(sortedVS, W_mlp1, W_mlp2, W_mlp3,
                                            W_mlp4, s1v1, payload, r0);
        k_agg<<<ga, 256, 0, stream>>>(payload, s1v1, off, agg, r0, r1,
                                      (c == 0) ? 1 : 0);
    }
    k_node_post<<<N_NODES, 256, 0, stream>>>(agg, W_down_s, W_down_v, out);
}

// Round 9
// 1276.742 us; speedup vs baseline: 4.8415x; 1.6366x over previous
//
#include <hip/hip_runtime.h>
#include <math.h>
#include <stdint.h>

#define N_NODES 50000
#define N_EDGES 800000
#define PLSTRIDE 132   // floats per edge payload
#define PL_SM  0       // smsg[64]
#define PL_B   64      // b[32] = mixv[0:32]
#define PL_A   96      // a[32] = C*mixv[32:64]
#define PL_SH  128     // sh[3]
#define PL_SND 131     // int
#define MLP_LDS 81920

__device__ __forceinline__ float silu_f(float x) {
    return x * __fdividef(1.f, 1.f + __expf(-x));
}

// ---------------- K1: per-node pre (s1,v1 -> ws; sc_s,sc_v -> out) ----------
__global__ void __launch_bounds__(256) k_node_pre(
    const float* __restrict__ node_feats,
    const int*   __restrict__ specie,
    const float* __restrict__ Wus,   // 32x32
    const float* __restrict__ Wuv,   // 32x32
    const float* __restrict__ Wss,   // 5x32x32
    const float* __restrict__ Wsv,   // 5x32x32
    float* __restrict__ s1v1,        // N x 128  [s1(32), v1 m*3+c (96)]
    float* __restrict__ out)         // N x 128  gets sc
{
    int n = blockIdx.x * 256 + threadIdx.x;
    if (n >= N_NODES) return;
    int part = blockIdx.y;           // 0 = scalar part, 1..3 = vector c
    const float* nf = node_feats + (size_t)n * 128;
    float* srow = s1v1 + (size_t)n * 128;
    float* orow = out  + (size_t)n * 128;
    int sp = specie[n];
    const float RS32 = 0.17677669529663687f; // 1/sqrt(32)

    if (part == 0) {
        float s[32];
        #pragma unroll
        for (int q = 0; q < 8; ++q) {
            float4 t = *reinterpret_cast<const float4*>(nf + 4*q);
            s[4*q+0]=t.x; s[4*q+1]=t.y; s[4*q+2]=t.z; s[4*q+3]=t.w;
        }
        float acc[32];
        #pragma unroll
        for (int k = 0; k < 32; ++k) acc[k] = 0.f;
        #pragma unroll
        for (int m = 0; m < 32; ++m) {
            float sm = s[m];
            #pragma unroll
            for (int k = 0; k < 32; ++k) acc[k] += sm * Wus[m*32 + k];
        }
        #pragma unroll
        for (int k = 0; k < 32; ++k) srow[k] = acc[k] * RS32;

        const float* Wp = Wss + sp * 1024;
        #pragma unroll
        for (int k = 0; k < 32; ++k) acc[k] = 0.f;
        #pragma unroll
        for (int i = 0; i < 32; ++i) {
            float si = s[i];
            #pragma unroll
            for (int j = 0; j < 32; ++j) acc[j] += si * __ldg(Wp + i*32 + j);
        }
        #pragma unroll
        for (int j = 0; j < 32; ++j) orow[j] = acc[j] * RS32;
    } else {
        int c = part - 1;
        float v[32];
        #pragma unroll
        for (int m = 0; m < 32; ++m) v[m] = nf[32 + m*3 + c];
        float acc[32];
        #pragma unroll
        for (int k = 0; k < 32; ++k) acc[k] = 0.f;
        #pragma unroll
        for (int m = 0; m < 32; ++m) {
            float vm = v[m];
            #pragma unroll
            for (int k = 0; k < 32; ++k) acc[k] += vm * Wuv[m*32 + k];
        }
        #pragma unroll
        for (int k = 0; k < 32; ++k) srow[32 + k*3 + c] = acc[k] * RS32;

        const float* Wp = Wsv + sp * 1024;
        #pragma unroll
        for (int k = 0; k < 32; ++k) acc[k] = 0.f;
        #pragma unroll
        for (int m = 0; m < 32; ++m) {
            float vm = v[m];
            #pragma unroll
            for (int k = 0; k < 32; ++k) acc[k] += vm * __ldg(Wp + m*32 + k);
        }
        #pragma unroll
        for (int k = 0; k < 32; ++k) orow[32 + k*3 + c] = acc[k] * RS32;
    }
}

// ---------------- sort stage: histogram -> scan -> scatter ------------------
__global__ void __launch_bounds__(256) k_hist(
    const int* __restrict__ receivers, int* __restrict__ cnt)
{
    int e = blockIdx.x * 256 + threadIdx.x;   // grid exact
    atomicAdd(&cnt[receivers[e]], 1);
}

__global__ void __launch_bounds__(1024) k_scan(
    const int* __restrict__ cnt, int* __restrict__ off, int* __restrict__ cursor)
{
    __shared__ int lds[1024];
    __shared__ int base_s;
    int t = threadIdx.x;
    if (t == 0) base_s = 0;
    __syncthreads();
    for (int start = 0; start < N_NODES; start += 1024) {
        int i = start + t;
        int c = (i < N_NODES) ? cnt[i] : 0;
        lds[t] = c;
        __syncthreads();
        for (int d = 1; d < 1024; d <<= 1) {
            int v = (t >= d) ? lds[t - d] : 0;
            __syncthreads();
            lds[t] += v;
            __syncthreads();
        }
        int excl = base_s + lds[t] - c;
        if (i < N_NODES) { off[i] = excl; cursor[i] = 0; }
        __syncthreads();
        if (t == 0) base_s += lds[1023];
        __syncthreads();
    }
    if (t == 0) off[N_NODES] = base_s;
}

__global__ void __launch_bounds__(256) k_scatter(
    const float* __restrict__ vectors, const int* __restrict__ senders,
    const int* __restrict__ receivers, const int* __restrict__ off,
    int* __restrict__ cursor, float4* __restrict__ sortedVS)
{
    int e = blockIdx.x * 256 + threadIdx.x;   // grid exact
    int r = receivers[e];
    int pos = off[r] + atomicAdd(&cursor[r], 1);
    float4 vs;
    vs.x = vectors[3*e+0]; vs.y = vectors[3*e+1]; vs.z = vectors[3*e+2];
    vs.w = __int_as_float(senders[e]);
    sortedVS[pos] = vs;
}

// ---------------- K2: tiled fp32 GEMM MLP over 128-edge blocks --------------
// LDS: bufA[64][128] | bufB[64][128] | Wl[64][64]  = 80 KB (2 blocks/CU)
// thread microtile: 4 edges x 8 neurons. Epilogue writes 528B payload/edge.
__global__ void __launch_bounds__(256, 2) k_mlp(
    const float4* __restrict__ sortedVS,
    const float* __restrict__ W1,    // 8x64
    const float* __restrict__ W2,    // 64x64
    const float* __restrict__ W3,    // 64x64
    const float* __restrict__ W4,    // 64x128
    const float* __restrict__ s1v1,  // N x 128
    float* __restrict__ payload,     // chunk rows x 132
    int r0)
{
    extern __shared__ float lds[];
    float* bufA = lds;           // 64*128
    float* bufB = lds + 8192;    // 64*128
    float* Wl   = lds + 16384;   // 64*64
    int t  = threadIdx.x;
    int e0 = (t & 31) * 4;
    int j0 = (t >> 5) * 8;
    int s0 = r0 + blockIdx.x * 128;
    float* payBlk = payload + (size_t)blockIdx.x * 128 * PLSTRIDE;

    const float RS8  = 0.35355339059327373f;
    const float RS64 = 0.125f;
    const float RS3  = 0.5773502691896258f;

    // ---- phase A: radial -> bufA rows 0..7 ; sh,snd -> payload ; W1 -> Wl --
    if (t < 128) {
        int e = t;
        float4 vs = sortedVS[s0 + e];
        float vx = vs.x, vy = vs.y, vz = vs.z;
        float x2 = vx*vx + vy*vy + vz*vz;
        float len = sqrtf(x2 == 0.f ? 1.f : x2);
        float invl = 1.f / len;
        float l2v = len*len, l3v = l2v*len, l6 = l3v*l3v;
        float env = (len < 1.f) ? (1.f - 28.f*l6 + 48.f*l6*len - 21.f*l6*l2v) : 0.f;
        const float SQRT2 = 1.4142135623730951f;
        const float PI    = 3.14159265358979f;
        #pragma unroll
        for (int nb = 0; nb < 8; ++nb)
            bufA[nb*128 + e] = SQRT2 * __sinf(PI * (float)(nb+1) * len) * invl * env;
        const float SQ3 = 1.7320508075688772f;
        float* pe = payBlk + (size_t)e * PLSTRIDE;
        pe[PL_SH+0] = SQ3 * vx * invl;
        pe[PL_SH+1] = SQ3 * vy * invl;
        pe[PL_SH+2] = SQ3 * vz * invl;
        ((int*)pe)[PL_SND] = __float_as_int(vs.w);
    } else {
        int i = t - 128;   // 128 float4 = 512 floats of W1
        reinterpret_cast<float4*>(Wl)[i] = reinterpret_cast<const float4*>(W1)[i];
    }
    __syncthreads();

    float acc[8][4];
    auto gemm = [&](const float* Xb, int kd) {
        #pragma unroll
        for (int jj = 0; jj < 8; ++jj)
            #pragma unroll
            for (int ee = 0; ee < 4; ++ee) acc[jj][ee] = 0.f;
        for (int k = 0; k < kd; ++k) {
            float4 xa = *reinterpret_cast<const float4*>(Xb + k*128 + e0);
            float4 w0 = *reinterpret_cast<const float4*>(Wl + k*64 + j0);
            float4 w1 = *reinterpret_cast<const float4*>(Wl + k*64 + j0 + 4);
            float w[8] = {w0.x,w0.y,w0.z,w0.w,w1.x,w1.y,w1.z,w1.w};
            float x[4] = {xa.x,xa.y,xa.z,xa.w};
            #pragma unroll
            for (int jj = 0; jj < 8; ++jj)
                #pragma unroll
                for (int ee = 0; ee < 4; ++ee) acc[jj][ee] += w[jj]*x[ee];
        }
    };
    auto act_store = [&](float* Yb, float sc) {
        #pragma unroll
        for (int jj = 0; jj < 8; ++jj) {
            float4 o;
            o.x = silu_f(acc[jj][0]*sc); o.y = silu_f(acc[jj][1]*sc);
            o.z = silu_f(acc[jj][2]*sc); o.w = silu_f(acc[jj][3]*sc);
            *reinterpret_cast<float4*>(Yb + (j0+jj)*128 + e0) = o;
        }
    };
    auto stageW = [&](const float* Wg) {       // 64x64 row-major
        #pragma unroll
        for (int i = t; i < 1024; i += 256)
            reinterpret_cast<float4*>(Wl)[i] = reinterpret_cast<const float4*>(Wg)[i];
    };
    auto stageW4 = [&](int q0) {               // W4 cols q0*4 .. q0*4+63
        #pragma unroll
        for (int i = t; i < 1024; i += 256) {
            int k = i >> 4, jq = i & 15;
            reinterpret_cast<float4*>(Wl)[i] =
                reinterpret_cast<const float4*>(W4)[k*32 + q0 + jq];
        }
    };

    // L1: radial(8) -> h1
    gemm(bufA, 8);
    __syncthreads();
    act_store(bufB, RS8);
    stageW(W2);
    __syncthreads();
    // L2: h1 -> h2
    gemm(bufB, 64);
    __syncthreads();
    act_store(bufA, RS64);
    stageW(W3);
    __syncthreads();
    // L3: h2 -> h3
    gemm(bufA, 64);
    __syncthreads();
    act_store(bufB, RS64);
    stageW4(0);
    __syncthreads();

    // pass 4a: mix_s = h3 @ W4[:,0:64] * RS64 ; epilogue -> smsg
    gemm(bufB, 64);
    #pragma unroll
    for (int ee = 0; ee < 4; ++ee) {
        int e = e0 + ee;
        float* pe = payBlk + (size_t)e * PLSTRIDE;
        int snd = ((const int*)pe)[PL_SND];
        const float* row = s1v1 + (size_t)snd * 128;
        float o[8];
        if (j0 < 32) {
            float4 c0 = *reinterpret_cast<const float4*>(row + j0);
            float4 c1 = *reinterpret_cast<const float4*>(row + j0 + 4);
            float cc[8] = {c0.x,c0.y,c0.z,c0.w,c1.x,c1.y,c1.z,c1.w};
            #pragma unroll
            for (int jj = 0; jj < 8; ++jj) o[jj] = cc[jj] * acc[jj][ee] * RS64;
        } else {
            float shx = pe[PL_SH], shy = pe[PL_SH+1], shz = pe[PL_SH+2];
            int base = 3*j0 - 64;            // 32 + 3*(j0-32), 16B aligned
            float r[28];
            #pragma unroll
            for (int q = 0; q < 7; ++q)
                *reinterpret_cast<float4*>(r + 4*q) =
                    *reinterpret_cast<const float4*>(row + base + 4*q);
            #pragma unroll
            for (int jj = 0; jj < 8; ++jj) {
                float D = (r[3*jj]*shx + r[3*jj+1]*shy + r[3*jj+2]*shz) * RS3;
                o[jj] = D * acc[jj][ee] * RS64;
            }
        }
        *reinterpret_cast<float4*>(pe + PL_SM + j0)     = make_float4(o[0],o[1],o[2],o[3]);
        *reinterpret_cast<float4*>(pe + PL_SM + j0 + 4) = make_float4(o[4],o[5],o[6],o[7]);
    }
    __syncthreads();
    stageW4(16);
    __syncthreads();

    // pass 4b: mix_v = h3 @ W4[:,64:128] * RS64 ; epilogue -> b (m<32), a (m>=32)
    gemm(bufB, 64);
    #pragma unroll
    for (int ee = 0; ee < 4; ++ee) {
        int e = e0 + ee;
        float* pe = payBlk + (size_t)e * PLSTRIDE;
        float o[8];
        if (j0 < 32) {
            #pragma unroll
            for (int jj = 0; jj < 8; ++jj) o[jj] = acc[jj][ee] * RS64;
            *reinterpret_cast<float4*>(pe + PL_B + j0)     = make_float4(o[0],o[1],o[2],o[3]);
            *reinterpret_cast<float4*>(pe + PL_B + j0 + 4) = make_float4(o[4],o[5],o[6],o[7]);
        } else {
            int snd = ((const int*)pe)[PL_SND];
            const float* row = s1v1 + (size_t)snd * 128;
            int m0 = j0 - 32;
            float4 c0 = *reinterpret_cast<const float4*>(row + m0);
            float4 c1 = *reinterpret_cast<const float4*>(row + m0 + 4);
            float cc[8] = {c0.x,c0.y,c0.z,c0.w,c1.x,c1.y,c1.z,c1.w};
            #pragma unroll
            for (int jj = 0; jj < 8; ++jj) o[jj] = cc[jj] * acc[jj][ee] * RS64;
            *reinterpret_cast<float4*>(pe + PL_A + m0)     = make_float4(o[0],o[1],o[2],o[3]);
            *reinterpret_cast<float4*>(pe + PL_A + m0 + 4) = make_float4(o[4],o[5],o[6],o[7]);
        }
    }
}

// ---------------- K2b: block-per-node aggregation, single coalesced pass ----
// Thread t owns component t; per edge the block reads the 132-float payload
// row cooperatively (coalesced, every line fully used). Payload streamed once.
__global__ void __launch_bounds__(256) k_agg(
    const float* __restrict__ payload,
    const float* __restrict__ s1v1,
    const int*   __restrict__ off,
    float* __restrict__ agg,         // N x 256
    int r0, int r1, int first)
{
    int n = blockIdx.x;
    int t = threadIdx.x;
    int p0 = off[n], p1 = off[n+1];
    int lo = p0 > r0 ? p0 : r0;
    int hi = p1 < r1 ? p1 : r1;
    if (!first && lo >= hi) return;

    float s = 0.f;
    if (t < 64) {
        const float* pp = payload + (size_t)(lo - r0) * PLSTRIDE + t;
        for (int p = lo; p < hi; ++p, pp += PLSTRIDE) s += *pp;
    } else if (t < 160) {
        int mc = t - 64;             // 0..95 -> v1 comp
        int m3 = mc / 3;             // b index 0..31
        const float* pp = payload + (size_t)(lo - r0) * PLSTRIDE;
        for (int p = lo; p < hi; ++p, pp += PLSTRIDE) {
            int snd = __float_as_int(pp[PL_SND]);
            s += s1v1[(size_t)snd * 128 + 32 + mc] * pp[PL_B + m3];
        }
    } else {
        int mc = t - 160;            // 0..95
        int m = mc / 3, c = mc - 3*m;
        const float* pp = payload + (size_t)(lo - r0) * PLSTRIDE;
        for (int p = lo; p < hi; ++p, pp += PLSTRIDE)
            s += pp[PL_A + m] * pp[PL_SH + c];
    }
    float* ap = agg + (size_t)n * 256 + t;
    if (first) *ap = s;
    else       *ap += s;
}

// ---------------- K3: per-node post (down-proj, gate, += into out) ----------
__global__ void __launch_bounds__(256) k_node_post(
    const float* __restrict__ agg,   // N x 256
    const float* __restrict__ Wds,   // 64x64
    const float* __restrict__ Wdv,   // 64x32
    float* __restrict__ out)         // N x 128 (holds sc from K1)
{
    int n = blockIdx.x;
    int t = threadIdx.x;
    __shared__ float a_s[256];
    __shared__ float gl[32];

    a_s[t] = agg[(size_t)n * 256 + t];
    __syncthreads();

    const float SC = 0.03125f;       // (1/sqrt(16)) * (1/sqrt(64))
    float* orow = out + (size_t)n * 128;

    float dv = 0.f;
    if (t < 64) {
        float acc = 0.f;
        #pragma unroll
        for (int m = 0; m < 64; ++m) acc += a_s[m] * Wds[m*64 + t];
        float sv = silu_f(acc * SC);
        if (t < 32) orow[t] += sv;       // feat + sc_s
        else        gl[t - 32] = sv;     // g
    } else if (t < 160) {
        int kc = t - 64;                 // = k*3 + c
        int k = kc / 3, c = kc - 3*k;
        float acc = 0.f;
        #pragma unroll
        for (int m = 0; m < 64; ++m) acc += a_s[64 + m*3 + c] * Wdv[m*32 + k];
        dv = acc * SC;
    }
    __syncthreads();
    if (t >= 64 && t < 160) {
        int kc = t - 64;
        int k = kc / 3;
        orow[32 + kc] += dv * gl[k];     // gv + sc_v
    }
}

extern "C" void kernel_launch(void* const* d_in, const int* in_sizes, int n_in,
                              void* d_out, int out_size, void* d_ws, size_t ws_size,
                              hipStream_t stream) {
    const float* vectors    = (const float*)d_in[0];
    const float* node_feats = (const float*)d_in[1];
    const float* W_skip_s   = (const float*)d_in[2];
    const float* W_skip_v   = (const float*)d_in[3];
    const float* W_up_s     = (const float*)d_in[4];
    const float* W_up_v     = (const float*)d_in[5];
    const float* W_mlp1     = (const float*)d_in[6];
    const float* W_mlp2     = (const float*)d_in[7];
    const float* W_mlp3     = (const float*)d_in[8];
    const float* W_mlp4     = (const float*)d_in[9];
    const float* W_down_s   = (const float*)d_in[10];
    const float* W_down_v   = (const float*)d_in[11];
    const int*   node_specie= (const int*)d_in[12];
    const int*   senders    = (const int*)d_in[13];
    const int*   receivers  = (const int*)d_in[14];
    float* out = (float*)d_out;

    // workspace layout
    float*  s1v1     = (float*)d_ws;                                   // N*128
    float*  agg      = s1v1 + (size_t)N_NODES * 128;                   // N*256
    float4* sortedVS = (float4*)(agg + (size_t)N_NODES * 256);         // E
    int*    cnt      = (int*)(sortedVS + N_EDGES);                     // N
    int*    cursor   = cnt + N_NODES;                                  // N
    int*    off      = cursor + N_NODES;                               // N+1
    char*   pb       = (char*)(off + N_NODES + 1);
    pb = (char*)(((uintptr_t)pb + 255) & ~(uintptr_t)255);
    float*  payload  = (float*)pb;

    size_t base_bytes = (size_t)(pb - (char*)d_ws);
    size_t margin = 1 << 20;
    size_t avail = (ws_size > base_bytes + margin) ? (ws_size - base_bytes - margin) : 0;
    long cap = (long)(avail / (PLSTRIDE * 4));
    if (cap > N_EDGES) cap = N_EDGES;
    if (cap < 12800)   cap = 12800;            // assume ws >= ~100 MB
    int  chunks = (int)((N_EDGES + cap - 1) / cap);
    long rows   = (((N_EDGES + chunks - 1) / chunks) + 127) & ~127L;   // mult of 128
    chunks = (int)((N_EDGES + rows - 1) / rows);

    hipFuncSetAttribute((const void*)k_mlp,
                        hipFuncAttributeMaxDynamicSharedMemorySize, MLP_LDS);

    hipMemsetAsync(cnt, 0, (size_t)N_NODES * sizeof(int), stream);

    dim3 gn((N_NODES + 255) / 256, 4);
    k_node_pre<<<gn, 256, 0, stream>>>(node_feats, node_specie, W_up_s, W_up_v,
                                       W_skip_s, W_skip_v, s1v1, out);
    k_hist<<<N_EDGES / 256, 256, 0, stream>>>(receivers, cnt);
    k_scan<<<1, 1024, 0, stream>>>(cnt, off, cursor);
    k_scatter<<<N_EDGES / 256, 256, 0, stream>>>(vectors, senders, receivers,
                                                 off, cursor, sortedVS);
    for (int c = 0; c < chunks; ++c) {
        int r0 = (int)(c * rows);
        int r1 = (int)(r0 + rows); if (r1 > N_EDGES) r1 = N_EDGES;
        int nb = (r1 - r0) / 128;
        k_mlp<<<nb, 256, MLP_LDS, stream>>>(sortedVS, W_mlp1, W_mlp2, W_mlp3,
                                            W_mlp4, s1v1, payload, r0);
        k_agg<<<N_NODES, 256, 0, stream>>>(payload, s1v1, off, agg, r0, r1,
                                           (c == 0) ? 1 : 0);
    }
    k_node_post<<<N_NODES, 256, 0, stream>>>(agg, W_down_s, W_down_v, out);
}